// Round 8
// baseline (375.124 us; speedup 1.0000x reference)
//
#include <hip/hip_runtime.h>
#include <hip/hip_bf16.h>

// Problem constants (B=8, L=4096, D=1024, S=256)
#define BB 8
#define LL 4096
#define DD 1024
#define SS 256
#define NTOK (BB * LL)  // 32768 tokens
#define CCH 64          // chunks per sequence (parallel scan)
#define TCH (LL / CCH)  // 64 timesteps per chunk

typedef short bf16x8 __attribute__((ext_vector_type(8)));
typedef float f32x4 __attribute__((ext_vector_type(4)));

__device__ __forceinline__ float bfu(unsigned short v) {
  union { unsigned int i; float f; } x;
  x.i = ((unsigned int)v) << 16;
  return x.f;
}

// Async global->LDS, 16B per lane. LDS dest is wave-uniform base + lane*16.
__device__ __forceinline__ void gl_lds16(const __hip_bfloat16* g, void* l) {
  __builtin_amdgcn_global_load_lds(
      (const __attribute__((address_space(1))) unsigned int*)g,
      (__attribute__((address_space(3))) unsigned int*)l, 16, 0, 0);
}

// ---------------------------------------------------------------------------
// Kernel 1: RMSNorm + bf16 cast.  One block per token row (D=1024).
// ---------------------------------------------------------------------------
__global__ __launch_bounds__(256) void prep_rms(const float* __restrict__ x,
                                                const float* __restrict__ wn,
                                                __hip_bfloat16* __restrict__ xn) {
  const size_t row = blockIdx.x;
  const int t = threadIdx.x;
  const float4 xv = reinterpret_cast<const float4*>(x + row * DD)[t];
  const float4 wv = reinterpret_cast<const float4*>(wn)[t];
  float ss = xv.x * xv.x + xv.y * xv.y + xv.z * xv.z + xv.w * xv.w;
#pragma unroll
  for (int m = 32; m >= 1; m >>= 1) ss += __shfl_xor(ss, m);
  __shared__ float red[4];
  if ((t & 63) == 0) red[t >> 6] = ss;
  __syncthreads();
  const float tot = red[0] + red[1] + red[2] + red[3];
  const float r = rsqrtf(tot * (1.0f / DD) + 1e-8f);
  union { ushort4 u; __hip_bfloat16 h[4]; } o;
  o.h[0] = __float2bfloat16(xv.x * wv.x * r);
  o.h[1] = __float2bfloat16(xv.y * wv.y * r);
  o.h[2] = __float2bfloat16(xv.z * wv.z * r);
  o.h[3] = __float2bfloat16(xv.w * wv.w * r);
  reinterpret_cast<ushort4*>(xn + row * DD)[t] = o.u;
}

// ---------------------------------------------------------------------------
// Kernel 2: all four weight transposes+casts in one launch (blockIdx.y = seg).
// WT[n*K+k] = bf16(W[k*Nw+n])
// ---------------------------------------------------------------------------
__global__ __launch_bounds__(256) void convT4(
    const float* __restrict__ W0, const float* __restrict__ W1,
    const float* __restrict__ W2, const float* __restrict__ W3,
    __hip_bfloat16* __restrict__ T0, __hip_bfloat16* __restrict__ T1,
    __hip_bfloat16* __restrict__ T2, __hip_bfloat16* __restrict__ T3) {
  const int seg = blockIdx.y;
  const int K = (seg == 0) ? DD : SS;
  const int Nw = (seg == 0) ? 768 : (seg == 3) ? DD : SS;
  const float* W = (seg == 0) ? W0 : (seg == 1) ? W1 : (seg == 2) ? W2 : W3;
  __hip_bfloat16* T = (seg == 0) ? T0 : (seg == 1) ? T1 : (seg == 2) ? T2 : T3;
  const int idx = blockIdx.x * 256 + threadIdx.x;
  if (idx >= K * Nw) return;
  const int k = idx / Nw, n = idx % Nw;
  T[(size_t)n * K + k] = __float2bfloat16(W[idx]);
}

// ---------------------------------------------------------------------------
// Kernel 3a: pipelined LDS GEMM for K=1024 (gemm0 only).
// 128x128 tile, 4 waves, BK=64, dbuf LDS, counted vmcnt, both-sides swizzle.
// EPI 0 = bf16 out.
// ---------------------------------------------------------------------------
template <int EPI>
__global__ __launch_bounds__(256, 2) void gemm_bf16(
    const __hip_bfloat16* __restrict__ A, int lda,
    const __hip_bfloat16* __restrict__ BT,  // [Nt][K] (pre-transposed)
    const float* __restrict__ bias,
    void* __restrict__ Cptr, int ldc,
    const float* __restrict__ resid,
    int K) {
  __shared__ __align__(16) char ldsA[2][128 * 128];
  __shared__ __align__(16) char ldsB[2][128 * 128];

  const int t = threadIdx.x;
  const int bm = blockIdx.x, bn = blockIdx.y;
  const int wave = t >> 6, lane = t & 63;
  const int wr = (wave >> 1) * 64;
  const int wc = (wave & 1) * 64;
  const int lr = lane & 15;
  const int kg = lane >> 4;
  const int rsw = lr & 7;

  const int srow = lane >> 3;
  const int sg = (lane & 7) ^ srow;
  const int g_row = wave * 32 + srow;
  const __hip_bfloat16* Ab = A + (size_t)(bm * 128 + g_row) * lda + sg * 8;
  const __hip_bfloat16* Bb = BT + (size_t)(bn * 128 + g_row) * K + sg * 8;

  f32x4 acc[4][4] = {};

#define STAGE(d, koff)                                                        \
  {                                                                           \
    _Pragma("unroll") for (int p = 0; p < 4; ++p) {                           \
      gl_lds16(Ab + (size_t)(p * 8) * lda + (koff),                           \
               ldsA[d] + (wave * 32 + p * 8) * 128);                          \
      gl_lds16(Bb + (size_t)(p * 8) * K + (koff),                             \
               ldsB[d] + (wave * 32 + p * 8) * 128);                          \
    }                                                                         \
  }

  const int NT = K >> 6;
  STAGE(0, 0);

  for (int ti = 0; ti < NT; ++ti) {
    const int cur = ti & 1;
    if (ti + 1 < NT) {
      STAGE(cur ^ 1, (ti + 1) * 64);
      asm volatile("s_waitcnt vmcnt(8)" ::: "memory");
    } else {
      asm volatile("s_waitcnt vmcnt(0)" ::: "memory");
    }
    __builtin_amdgcn_sched_barrier(0);
    __builtin_amdgcn_s_barrier();
#pragma unroll
    for (int kh = 0; kh < 2; ++kh) {
      bf16x8 af[4], bfr[4];
#pragma unroll
      for (int m = 0; m < 4; ++m) {
        const int row = wr + m * 16 + lr;
        const int slot = (kg + kh * 4) ^ rsw;
        af[m] = *reinterpret_cast<const bf16x8*>(ldsA[cur] + row * 128 + slot * 16);
      }
#pragma unroll
      for (int n = 0; n < 4; ++n) {
        const int row = wc + n * 16 + lr;
        const int slot = (kg + kh * 4) ^ rsw;
        bfr[n] = *reinterpret_cast<const bf16x8*>(ldsB[cur] + row * 128 + slot * 16);
      }
#pragma unroll
      for (int m = 0; m < 4; ++m)
#pragma unroll
        for (int n = 0; n < 4; ++n)
          acc[m][n] = __builtin_amdgcn_mfma_f32_16x16x32_bf16(bfr[n], af[m],
                                                              acc[m][n], 0, 0, 0);
    }
    __builtin_amdgcn_sched_barrier(0);
    __builtin_amdgcn_s_barrier();
  }
#undef STAGE

  const int row0 = bm * 128 + wr + lr;
  const int col0 = bn * 128 + wc + kg * 4;
#pragma unroll
  for (int m = 0; m < 4; ++m) {
    const int row = row0 + m * 16;
#pragma unroll
    for (int n = 0; n < 4; ++n) {
      const int colb = col0 + n * 16;
      const float4 bv = *reinterpret_cast<const float4*>(&bias[colb]);
      float v0 = acc[m][n][0] + bv.x;
      float v1 = acc[m][n][1] + bv.y;
      float v2 = acc[m][n][2] + bv.z;
      float v3 = acc[m][n][3] + bv.w;
      union { ushort4 u; __hip_bfloat16 h[4]; } o;
      o.h[0] = __float2bfloat16(v0); o.h[1] = __float2bfloat16(v1);
      o.h[2] = __float2bfloat16(v2); o.h[3] = __float2bfloat16(v3);
      *reinterpret_cast<ushort4*>(
          &((__hip_bfloat16*)Cptr)[(size_t)row * ldc + colb]) = o.u;
    }
  }
}

// ---------------------------------------------------------------------------
// Kernel 3b: NO-LDS register GEMM for K=256 (g1/g2/g3).  B (<=512KB) and the
// block's A-tile (64KB) are L2-resident; fragments load straight from global.
// No barriers, no LDS -> waves drift freely, epilogue overlaps compute.
// Tile: 128 rows x (NBN*128) cols per block; grid.y splits remaining N.
// EPI: 1 = tanh->bf16, 2 = sigmoid->bf16, 3 = +resid -> f32
// ---------------------------------------------------------------------------
template <int EPI, int NBN>
__global__ __launch_bounds__(256, 4) void gemm_k256(
    const __hip_bfloat16* __restrict__ A, int lda,
    const __hip_bfloat16* __restrict__ BT,  // [N][256]
    const float* __restrict__ bias,
    void* __restrict__ Cptr, int ldc,
    const float* __restrict__ resid) {
  const int t = threadIdx.x;
  const int bm = blockIdx.x;
  const int wave = t >> 6, lane = t & 63;
  const int wr = (wave >> 1) * 64;
  const int wc = (wave & 1) * 64;
  const int lr = lane & 15;
  const int kg = lane >> 4;

  const __hip_bfloat16* Abase =
      A + (size_t)(bm * 128 + wr + lr) * lda + kg * 8;

#pragma unroll
  for (int bn = 0; bn < NBN; ++bn) {
    const int ncol = (blockIdx.y * NBN + bn) * 128 + wc;  // tile col base
    f32x4 acc[4][4] = {};
#pragma unroll
    for (int s = 0; s < 8; ++s) {  // K = 8 slices of 32
      bf16x8 af[4], bfr[4];
#pragma unroll
      for (int m = 0; m < 4; ++m)
        af[m] = *reinterpret_cast<const bf16x8*>(
            Abase + (size_t)(m * 16) * lda + s * 32);
#pragma unroll
      for (int n = 0; n < 4; ++n)
        bfr[n] = *reinterpret_cast<const bf16x8*>(
            BT + (size_t)(ncol + n * 16 + lr) * 256 + s * 32 + kg * 8);
#pragma unroll
      for (int m = 0; m < 4; ++m)
#pragma unroll
        for (int n = 0; n < 4; ++n)
          acc[m][n] = __builtin_amdgcn_mfma_f32_16x16x32_bf16(bfr[n], af[m],
                                                              acc[m][n], 0, 0, 0);
    }
    // Epilogue: row = token, 4 consecutive C-cols per acc reg.
    const int row0 = bm * 128 + wr + lr;
    const int col0 = ncol + kg * 4;
#pragma unroll
    for (int m = 0; m < 4; ++m) {
      const int row = row0 + m * 16;
#pragma unroll
      for (int n = 0; n < 4; ++n) {
        const int colb = col0 + n * 16;
        const float4 bv = *reinterpret_cast<const float4*>(&bias[colb]);
        float v0 = acc[m][n][0] + bv.x;
        float v1 = acc[m][n][1] + bv.y;
        float v2 = acc[m][n][2] + bv.z;
        float v3 = acc[m][n][3] + bv.w;
        if (EPI == 3) {
          const size_t off = (size_t)row * ldc + colb;
          const float4 rv = *reinterpret_cast<const float4*>(&resid[off]);
          float4 ov;
          ov.x = v0 + rv.x; ov.y = v1 + rv.y; ov.z = v2 + rv.z; ov.w = v3 + rv.w;
          *reinterpret_cast<float4*>(&((float*)Cptr)[off]) = ov;
        } else {
          if (EPI == 1) {
            v0 = tanhf(v0); v1 = tanhf(v1); v2 = tanhf(v2); v3 = tanhf(v3);
          } else if (EPI == 2) {
            v0 = 1.f / (1.f + expf(-v0)); v1 = 1.f / (1.f + expf(-v1));
            v2 = 1.f / (1.f + expf(-v2)); v3 = 1.f / (1.f + expf(-v3));
          }
          union { ushort4 u; __hip_bfloat16 h[4]; } o;
          o.h[0] = __float2bfloat16(v0); o.h[1] = __float2bfloat16(v1);
          o.h[2] = __float2bfloat16(v2); o.h[3] = __float2bfloat16(v3);
          *reinterpret_cast<ushort4*>(
              &((__hip_bfloat16*)Cptr)[(size_t)row * ldc + colb]) = o.u;
        }
      }
    }
  }
}

// ---------------------------------------------------------------------------
// Kernel 4a: chunked scan phase A.  Per (b, chunk, s): local scan from h=0
// giving h0, and decay product A = prod(1-d).  2 channels per lane (ushort2).
// ---------------------------------------------------------------------------
__global__ __launch_bounds__(128) void scan_phase_a(
    const __hip_bfloat16* __restrict__ ut,
    const __hip_bfloat16* __restrict__ dtb,
    float* __restrict__ h0s, float* __restrict__ As) {
  const int bc = blockIdx.x;             // b*CCH + c
  const int b = bc / CCH, c = bc % CCH;
  const int ch = threadIdx.x * 2;        // channel pair base
  const size_t base = ((size_t)b * LL + (size_t)c * TCH) * SS + ch;
  float h0 = 0.f, h1 = 0.f, A0 = 1.f, A1 = 1.f;
#pragma unroll 8
  for (int t = 0; t < TCH; ++t) {
    const ushort2 uu = *reinterpret_cast<const ushort2*>(ut + base + (size_t)t * SS);
    const ushort2 dd = *reinterpret_cast<const ushort2*>(dtb + base + (size_t)t * SS);
    const float d0 = bfu(dd.x), d1 = bfu(dd.y);
    h0 = fmaf(d0, bfu(uu.x) - h0, h0);
    h1 = fmaf(d1, bfu(uu.y) - h1, h1);
    A0 *= (1.f - d0);
    A1 *= (1.f - d1);
  }
  const size_t o = (size_t)bc * SS + ch;
  *reinterpret_cast<float2*>(h0s + o) = make_float2(h0, h1);
  *reinterpret_cast<float2*>(As + o) = make_float2(A0, A1);
}

// ---------------------------------------------------------------------------
// Kernel 4b: carry scan over chunk summaries.  Per (b, s): hin_0 = 0,
// hin_{c+1} = h0_c + A_c * hin_c.  Stores hin per (b, c, s).
// ---------------------------------------------------------------------------
__global__ __launch_bounds__(256) void scan_phase_b(
    const float* __restrict__ h0s, const float* __restrict__ As,
    float* __restrict__ hins) {
  const int b = blockIdx.x;
  const int s = threadIdx.x;
  float hin = 0.f;
#pragma unroll 8
  for (int c = 0; c < CCH; ++c) {
    const size_t idx = ((size_t)b * CCH + c) * SS + s;
    hins[idx] = hin;
    hin = fmaf(As[idx], hin, h0s[idx]);
  }
}

// ---------------------------------------------------------------------------
// Kernel 4c: chunked scan phase C.  Re-run each chunk with correct carry-in,
// gate by sigmoid(g), write hsg (in-place over ut: same-thread read-first).
// ---------------------------------------------------------------------------
__global__ __launch_bounds__(128) void scan_phase_c(
    const __hip_bfloat16* __restrict__ ut,
    const __hip_bfloat16* __restrict__ dtb,
    const __hip_bfloat16* __restrict__ gz,   // uzg + 512, row stride 768
    const float* __restrict__ hins,
    __hip_bfloat16* __restrict__ hsg) {
  const int bc = blockIdx.x;
  const int b = bc / CCH, c = bc % CCH;
  const int ch = threadIdx.x * 2;
  const size_t rowbase = (size_t)b * LL + (size_t)c * TCH;
  const float2 hv = *reinterpret_cast<const float2*>(hins + (size_t)bc * SS + ch);
  float h0 = hv.x, h1 = hv.y;
#pragma unroll 8
  for (int t = 0; t < TCH; ++t) {
    const size_t row = rowbase + t;
    const ushort2 uu = *reinterpret_cast<const ushort2*>(ut + row * SS + ch);
    const ushort2 dd = *reinterpret_cast<const ushort2*>(dtb + row * SS + ch);
    const ushort2 gg = *reinterpret_cast<const ushort2*>(gz + row * 768 + ch);
    h0 = fmaf(bfu(dd.x), bfu(uu.x) - h0, h0);
    h1 = fmaf(bfu(dd.y), bfu(uu.y) - h1, h1);
    union { ushort2 u; __hip_bfloat16 h[2]; } o;
    o.h[0] = __float2bfloat16(h0 / (1.f + expf(-bfu(gg.x))));
    o.h[1] = __float2bfloat16(h1 / (1.f + expf(-bfu(gg.y))));
    *reinterpret_cast<ushort2*>(hsg + row * SS + ch) = o.u;
  }
}

// ---------------------------------------------------------------------------
extern "C" void kernel_launch(void* const* d_in, const int* in_sizes, int n_in,
                              void* d_out, int out_size, void* d_ws, size_t ws_size,
                              hipStream_t stream) {
  const float* x      = (const float*)d_in[0];
  const float* w_norm = (const float*)d_in[1];
  const float* W_in   = (const float*)d_in[2];
  const float* b_in   = (const float*)d_in[3];
  const float* W_x    = (const float*)d_in[4];
  const float* b_x    = (const float*)d_in[5];
  const float* W_dt   = (const float*)d_in[6];
  const float* b_dt   = (const float*)d_in[7];
  const float* W_out  = (const float*)d_in[8];
  const float* b_out  = (const float*)d_in[9];
  float* out = (float*)d_out;

  // Workspace layout (bf16 buffers). ut/dt alias the dead xn region.
  char* w = (char*)d_ws;
  __hip_bfloat16* xn  = (__hip_bfloat16*)w;                 // NTOK*1024
  __hip_bfloat16* ut  = (__hip_bfloat16*)w;                 // NTOK*256 (after GEMM1)
  __hip_bfloat16* dtb = (__hip_bfloat16*)(w + (size_t)NTOK * SS * 2);
  w += (size_t)NTOK * DD * 2;                               // 64 MiB
  __hip_bfloat16* uzg = (__hip_bfloat16*)w;  w += (size_t)NTOK * 768 * 2;  // 48 MiB
  __hip_bfloat16* WinT  = (__hip_bfloat16*)w;  w += (size_t)768 * DD * 2;
  __hip_bfloat16* WxT   = (__hip_bfloat16*)w;  w += (size_t)SS * SS * 2;
  __hip_bfloat16* WdtT  = (__hip_bfloat16*)w;  w += (size_t)SS * SS * 2;
  __hip_bfloat16* WoutT = (__hip_bfloat16*)w;  w += (size_t)DD * SS * 2;
  float* h0s  = (float*)w;  w += (size_t)BB * CCH * SS * 4;   // 512 KiB
  float* As   = (float*)w;  w += (size_t)BB * CCH * SS * 4;
  float* hins = (float*)w;  w += (size_t)BB * CCH * SS * 4;
  (void)ws_size; (void)n_in; (void)in_sizes; (void)out_size;

  // Stage 0: all weight conversions in one launch
  convT4<<<dim3((DD * 768 + 255) / 256, 4), 256, 0, stream>>>(
      W_in, W_x, W_dt, W_out, WinT, WxT, WdtT, WoutT);

  // Stage 1: RMSNorm -> xn (bf16)
  prep_rms<<<NTOK, 256, 0, stream>>>(x, w_norm, xn);

  // Stage 2: uzg = xn @ W_in + b_in   (M=32768, N=768, K=1024)
  gemm_bf16<0><<<dim3(NTOK / 128, 768 / 128), 256, 0, stream>>>(
      xn, DD, WinT, b_in, uzg, 768, nullptr, DD);

  // Stage 3: ut = tanh(u @ W_x + b_x); dt = sigmoid(z @ W_dt + b_dt)
  gemm_k256<1, 1><<<dim3(NTOK / 128, 2), 256, 0, stream>>>(
      uzg, 768, WxT, b_x, ut, SS, nullptr);
  gemm_k256<2, 1><<<dim3(NTOK / 128, 2), 256, 0, stream>>>(
      uzg + SS, 768, WdtT, b_dt, dtb, SS, nullptr);

  // Stage 4: chunked parallel scan + gate (in-place hsg over ut buffer)
  scan_phase_a<<<BB * CCH, 128, 0, stream>>>(ut, dtb, h0s, As);
  scan_phase_b<<<BB, 256, 0, stream>>>(h0s, As, hins);
  scan_phase_c<<<BB * CCH, 128, 0, stream>>>(ut, dtb, uzg + 2 * SS, hins, ut);

  // Stage 5: out = x + hsg @ W_out + b_out  (M=32768, N=1024, K=256)
  gemm_k256<3, 2><<<dim3(NTOK / 128, 4), 256, 0, stream>>>(
      ut, SS, WoutT, b_out, out, DD, x);
}

// Round 10
// 282.699 us; speedup vs baseline: 1.3269x; 1.3269x over previous
//
#include <hip/hip_runtime.h>
#include <hip/hip_bf16.h>

// Problem constants (B=8, L=4096, D=1024, S=256)
#define BB 8
#define LL 4096
#define DD 1024
#define SS 256
#define NTOK (BB * LL)  // 32768 tokens
#define CCH 64          // chunks per sequence (parallel scan)
#define TCH (LL / CCH)  // 64 timesteps per chunk

typedef short bf16x8 __attribute__((ext_vector_type(8)));
typedef float f32x4 __attribute__((ext_vector_type(4)));

__device__ __forceinline__ float bfu(unsigned short v) {
  union { unsigned int i; float f; } x;
  x.i = ((unsigned int)v) << 16;
  return x.f;
}

// Async global->LDS, 16B per lane. LDS dest is wave-uniform base + lane*16.
__device__ __forceinline__ void gl_lds16(const __hip_bfloat16* g, void* l) {
  __builtin_amdgcn_global_load_lds(
      (const __attribute__((address_space(1))) unsigned int*)g,
      (__attribute__((address_space(3))) unsigned int*)l, 16, 0, 0);
}

// ---------------------------------------------------------------------------
// Kernel 1: RMSNorm + bf16 cast.  One block per token row (D=1024).
// ---------------------------------------------------------------------------
__global__ __launch_bounds__(256) void prep_rms(const float* __restrict__ x,
                                                const float* __restrict__ wn,
                                                __hip_bfloat16* __restrict__ xn) {
  const size_t row = blockIdx.x;
  const int t = threadIdx.x;
  const float4 xv = reinterpret_cast<const float4*>(x + row * DD)[t];
  const float4 wv = reinterpret_cast<const float4*>(wn)[t];
  float ss = xv.x * xv.x + xv.y * xv.y + xv.z * xv.z + xv.w * xv.w;
#pragma unroll
  for (int m = 32; m >= 1; m >>= 1) ss += __shfl_xor(ss, m);
  __shared__ float red[4];
  if ((t & 63) == 0) red[t >> 6] = ss;
  __syncthreads();
  const float tot = red[0] + red[1] + red[2] + red[3];
  const float r = rsqrtf(tot * (1.0f / DD) + 1e-8f);
  union { ushort4 u; __hip_bfloat16 h[4]; } o;
  o.h[0] = __float2bfloat16(xv.x * wv.x * r);
  o.h[1] = __float2bfloat16(xv.y * wv.y * r);
  o.h[2] = __float2bfloat16(xv.z * wv.z * r);
  o.h[3] = __float2bfloat16(xv.w * wv.w * r);
  reinterpret_cast<ushort4*>(xn + row * DD)[t] = o.u;
}

// ---------------------------------------------------------------------------
// Kernel 2: all four weight transposes+casts in one launch (blockIdx.y = seg).
// WT[n*K+k] = bf16(W[k*Nw+n])
// ---------------------------------------------------------------------------
__global__ __launch_bounds__(256) void convT4(
    const float* __restrict__ W0, const float* __restrict__ W1,
    const float* __restrict__ W2, const float* __restrict__ W3,
    __hip_bfloat16* __restrict__ T0, __hip_bfloat16* __restrict__ T1,
    __hip_bfloat16* __restrict__ T2, __hip_bfloat16* __restrict__ T3) {
  const int seg = blockIdx.y;
  const int K = (seg == 0) ? DD : SS;
  const int Nw = (seg == 0) ? 768 : (seg == 3) ? DD : SS;
  const float* W = (seg == 0) ? W0 : (seg == 1) ? W1 : (seg == 2) ? W2 : W3;
  __hip_bfloat16* T = (seg == 0) ? T0 : (seg == 1) ? T1 : (seg == 2) ? T2 : T3;
  const int idx = blockIdx.x * 256 + threadIdx.x;
  if (idx >= K * Nw) return;
  const int k = idx / Nw, n = idx % Nw;
  T[(size_t)n * K + k] = __float2bfloat16(W[idx]);
}

// ---------------------------------------------------------------------------
// Kernel 3: bf16 MFMA GEMM.  C[M,Nt] = epi(A[M,K] @ BT[Nt,K]^T + bias)
// 128x128 tile, 4 waves, BK=64, dbuf LDS, counted vmcnt (T4), both-sides
// XOR swizzle (T2/rule #21), swapped MFMA operands (row=token epilogue).
// EPI 3: hoisted nontemporal resid loads (16 in flight/wave) + NT stores —
// resid/out are stream-once, keep them out of L2; maximize epilogue MLP.
// EPI: 0 = bf16 out, 1 = tanh->bf16, 2 = sigmoid->bf16, 3 = +resid -> f32
// ---------------------------------------------------------------------------
template <int EPI>
__global__ __launch_bounds__(256, 2) void gemm_bf16(
    const __hip_bfloat16* __restrict__ A, int lda,
    const __hip_bfloat16* __restrict__ BT,  // [Nt][K] (pre-transposed)
    const float* __restrict__ bias,
    void* __restrict__ Cptr, int ldc,
    const float* __restrict__ resid,
    int K) {
  __shared__ __align__(16) char ldsA[2][128 * 128];
  __shared__ __align__(16) char ldsB[2][128 * 128];

  const int t = threadIdx.x;
  const int bm = blockIdx.x, bn = blockIdx.y;
  const int wave = t >> 6, lane = t & 63;
  const int wr = (wave >> 1) * 64;
  const int wc = (wave & 1) * 64;
  const int lr = lane & 15;
  const int kg = lane >> 4;
  const int rsw = lr & 7;

  const int srow = lane >> 3;
  const int sg = (lane & 7) ^ srow;
  const int g_row = wave * 32 + srow;
  const __hip_bfloat16* Ab = A + (size_t)(bm * 128 + g_row) * lda + sg * 8;
  const __hip_bfloat16* Bb = BT + (size_t)(bn * 128 + g_row) * K + sg * 8;

  f32x4 acc[4][4] = {};

#define STAGE(d, koff)                                                        \
  {                                                                           \
    _Pragma("unroll") for (int p = 0; p < 4; ++p) {                           \
      gl_lds16(Ab + (size_t)(p * 8) * lda + (koff),                           \
               ldsA[d] + (wave * 32 + p * 8) * 128);                          \
      gl_lds16(Bb + (size_t)(p * 8) * K + (koff),                             \
               ldsB[d] + (wave * 32 + p * 8) * 128);                          \
    }                                                                         \
  }

  const int NT = K >> 6;
  STAGE(0, 0);

  for (int ti = 0; ti < NT; ++ti) {
    const int cur = ti & 1;
    if (ti + 1 < NT) {
      STAGE(cur ^ 1, (ti + 1) * 64);
      asm volatile("s_waitcnt vmcnt(8)" ::: "memory");
    } else {
      asm volatile("s_waitcnt vmcnt(0)" ::: "memory");
    }
    __builtin_amdgcn_sched_barrier(0);
    __builtin_amdgcn_s_barrier();
#pragma unroll
    for (int kh = 0; kh < 2; ++kh) {
      bf16x8 af[4], bfr[4];
#pragma unroll
      for (int m = 0; m < 4; ++m) {
        const int row = wr + m * 16 + lr;
        const int slot = (kg + kh * 4) ^ rsw;
        af[m] = *reinterpret_cast<const bf16x8*>(ldsA[cur] + row * 128 + slot * 16);
      }
#pragma unroll
      for (int n = 0; n < 4; ++n) {
        const int row = wc + n * 16 + lr;
        const int slot = (kg + kh * 4) ^ rsw;
        bfr[n] = *reinterpret_cast<const bf16x8*>(ldsB[cur] + row * 128 + slot * 16);
      }
#pragma unroll
      for (int m = 0; m < 4; ++m)
#pragma unroll
        for (int n = 0; n < 4; ++n)
          acc[m][n] = __builtin_amdgcn_mfma_f32_16x16x32_bf16(bfr[n], af[m],
                                                              acc[m][n], 0, 0, 0);
    }
    __builtin_amdgcn_sched_barrier(0);
    __builtin_amdgcn_s_barrier();
  }
#undef STAGE

  // Swapped-operand epilogue:
  // token row = bm*128 + wr + m*16 + (lane&15)
  // C col     = bn*128 + wc + n*16 + kg*4 + j   (j = 0..3 consecutive)
  const int row0 = bm * 128 + wr + lr;
  const int col0 = bn * 128 + wc + kg * 4;

  if (EPI == 3) {
    // Hoist ALL 16 resid loads (nontemporal) -> 16 KB in flight per wave.
    f32x4 rv[4][4];
#pragma unroll
    for (int m = 0; m < 4; ++m) {
      const size_t rowoff = (size_t)(row0 + m * 16) * ldc;
#pragma unroll
      for (int n = 0; n < 4; ++n) {
        rv[m][n] = __builtin_nontemporal_load(
            reinterpret_cast<const f32x4*>(&resid[rowoff + col0 + n * 16]));
      }
    }
#pragma unroll
    for (int m = 0; m < 4; ++m) {
      const size_t rowoff = (size_t)(row0 + m * 16) * ldc;
#pragma unroll
      for (int n = 0; n < 4; ++n) {
        const int colb = col0 + n * 16;
        const f32x4 bv = *reinterpret_cast<const f32x4*>(&bias[colb]);
        f32x4 ov = acc[m][n] + bv + rv[m][n];
        __builtin_nontemporal_store(
            ov, reinterpret_cast<f32x4*>(&((float*)Cptr)[rowoff + colb]));
      }
    }
  } else {
#pragma unroll
    for (int m = 0; m < 4; ++m) {
      const int row = row0 + m * 16;
#pragma unroll
      for (int n = 0; n < 4; ++n) {
        const int colb = col0 + n * 16;
        const float4 bv = *reinterpret_cast<const float4*>(&bias[colb]);
        float v0 = acc[m][n][0] + bv.x;
        float v1 = acc[m][n][1] + bv.y;
        float v2 = acc[m][n][2] + bv.z;
        float v3 = acc[m][n][3] + bv.w;
        if (EPI == 1) {
          v0 = tanhf(v0); v1 = tanhf(v1); v2 = tanhf(v2); v3 = tanhf(v3);
        } else if (EPI == 2) {
          v0 = 1.f / (1.f + expf(-v0)); v1 = 1.f / (1.f + expf(-v1));
          v2 = 1.f / (1.f + expf(-v2)); v3 = 1.f / (1.f + expf(-v3));
        }
        union { ushort4 u; __hip_bfloat16 h[4]; } o;
        o.h[0] = __float2bfloat16(v0); o.h[1] = __float2bfloat16(v1);
        o.h[2] = __float2bfloat16(v2); o.h[3] = __float2bfloat16(v3);
        *reinterpret_cast<ushort4*>(
            &((__hip_bfloat16*)Cptr)[(size_t)row * ldc + colb]) = o.u;
      }
    }
  }
}

// ---------------------------------------------------------------------------
// Kernel 4a: chunked scan phase A.  Per (b, chunk, s): local scan from h=0
// giving h0, and decay product A = prod(1-d).  2 channels per lane (ushort2).
// ---------------------------------------------------------------------------
__global__ __launch_bounds__(128) void scan_phase_a(
    const __hip_bfloat16* __restrict__ ut,
    const __hip_bfloat16* __restrict__ dtb,
    float* __restrict__ h0s, float* __restrict__ As) {
  const int bc = blockIdx.x;             // b*CCH + c
  const int b = bc / CCH, c = bc % CCH;
  const int ch = threadIdx.x * 2;        // channel pair base
  const size_t base = ((size_t)b * LL + (size_t)c * TCH) * SS + ch;
  float h0 = 0.f, h1 = 0.f, A0 = 1.f, A1 = 1.f;
#pragma unroll 8
  for (int t = 0; t < TCH; ++t) {
    const ushort2 uu = *reinterpret_cast<const ushort2*>(ut + base + (size_t)t * SS);
    const ushort2 dd = *reinterpret_cast<const ushort2*>(dtb + base + (size_t)t * SS);
    const float d0 = bfu(dd.x), d1 = bfu(dd.y);
    h0 = fmaf(d0, bfu(uu.x) - h0, h0);
    h1 = fmaf(d1, bfu(uu.y) - h1, h1);
    A0 *= (1.f - d0);
    A1 *= (1.f - d1);
  }
  const size_t o = (size_t)bc * SS + ch;
  *reinterpret_cast<float2*>(h0s + o) = make_float2(h0, h1);
  *reinterpret_cast<float2*>(As + o) = make_float2(A0, A1);
}

// ---------------------------------------------------------------------------
// Kernel 4b: carry scan over chunk summaries.  Per (b, s): hin_0 = 0,
// hin_{c+1} = h0_c + A_c * hin_c.  Stores hin per (b, c, s).
// ---------------------------------------------------------------------------
__global__ __launch_bounds__(256) void scan_phase_b(
    const float* __restrict__ h0s, const float* __restrict__ As,
    float* __restrict__ hins) {
  const int b = blockIdx.x;
  const int s = threadIdx.x;
  float hin = 0.f;
#pragma unroll 8
  for (int c = 0; c < CCH; ++c) {
    const size_t idx = ((size_t)b * CCH + c) * SS + s;
    hins[idx] = hin;
    hin = fmaf(As[idx], hin, h0s[idx]);
  }
}

// ---------------------------------------------------------------------------
// Kernel 4c: chunked scan phase C.  Re-run each chunk with correct carry-in,
// gate by sigmoid(g), write hsg (in-place over ut: same-thread read-first).
// ---------------------------------------------------------------------------
__global__ __launch_bounds__(128) void scan_phase_c(
    const __hip_bfloat16* __restrict__ ut,
    const __hip_bfloat16* __restrict__ dtb,
    const __hip_bfloat16* __restrict__ gz,   // uzg + 512, row stride 768
    const float* __restrict__ hins,
    __hip_bfloat16* __restrict__ hsg) {
  const int bc = blockIdx.x;
  const int b = bc / CCH, c = bc % CCH;
  const int ch = threadIdx.x * 2;
  const size_t rowbase = (size_t)b * LL + (size_t)c * TCH;
  const float2 hv = *reinterpret_cast<const float2*>(hins + (size_t)bc * SS + ch);
  float h0 = hv.x, h1 = hv.y;
#pragma unroll 8
  for (int t = 0; t < TCH; ++t) {
    const size_t row = rowbase + t;
    const ushort2 uu = *reinterpret_cast<const ushort2*>(ut + row * SS + ch);
    const ushort2 dd = *reinterpret_cast<const ushort2*>(dtb + row * SS + ch);
    const ushort2 gg = *reinterpret_cast<const ushort2*>(gz + row * 768 + ch);
    h0 = fmaf(bfu(dd.x), bfu(uu.x) - h0, h0);
    h1 = fmaf(bfu(dd.y), bfu(uu.y) - h1, h1);
    union { ushort2 u; __hip_bfloat16 h[2]; } o;
    o.h[0] = __float2bfloat16(h0 / (1.f + expf(-bfu(gg.x))));
    o.h[1] = __float2bfloat16(h1 / (1.f + expf(-bfu(gg.y))));
    *reinterpret_cast<ushort2*>(hsg + row * SS + ch) = o.u;
  }
}

// ---------------------------------------------------------------------------
extern "C" void kernel_launch(void* const* d_in, const int* in_sizes, int n_in,
                              void* d_out, int out_size, void* d_ws, size_t ws_size,
                              hipStream_t stream) {
  const float* x      = (const float*)d_in[0];
  const float* w_norm = (const float*)d_in[1];
  const float* W_in   = (const float*)d_in[2];
  const float* b_in   = (const float*)d_in[3];
  const float* W_x    = (const float*)d_in[4];
  const float* b_x    = (const float*)d_in[5];
  const float* W_dt   = (const float*)d_in[6];
  const float* b_dt   = (const float*)d_in[7];
  const float* W_out  = (const float*)d_in[8];
  const float* b_out  = (const float*)d_in[9];
  float* out = (float*)d_out;

  // Workspace layout (bf16 buffers). ut/dt alias the dead xn region.
  char* w = (char*)d_ws;
  __hip_bfloat16* xn  = (__hip_bfloat16*)w;                 // NTOK*1024
  __hip_bfloat16* ut  = (__hip_bfloat16*)w;                 // NTOK*256 (after GEMM1)
  __hip_bfloat16* dtb = (__hip_bfloat16*)(w + (size_t)NTOK * SS * 2);
  w += (size_t)NTOK * DD * 2;                               // 64 MiB
  __hip_bfloat16* uzg = (__hip_bfloat16*)w;  w += (size_t)NTOK * 768 * 2;  // 48 MiB
  __hip_bfloat16* WinT  = (__hip_bfloat16*)w;  w += (size_t)768 * DD * 2;
  __hip_bfloat16* WxT   = (__hip_bfloat16*)w;  w += (size_t)SS * SS * 2;
  __hip_bfloat16* WdtT  = (__hip_bfloat16*)w;  w += (size_t)SS * SS * 2;
  __hip_bfloat16* WoutT = (__hip_bfloat16*)w;  w += (size_t)DD * SS * 2;
  float* h0s  = (float*)w;  w += (size_t)BB * CCH * SS * 4;   // 512 KiB
  float* As   = (float*)w;  w += (size_t)BB * CCH * SS * 4;
  float* hins = (float*)w;  w += (size_t)BB * CCH * SS * 4;
  (void)ws_size; (void)n_in; (void)in_sizes; (void)out_size;

  // Stage 0: all weight conversions in one launch
  convT4<<<dim3((DD * 768 + 255) / 256, 4), 256, 0, stream>>>(
      W_in, W_x, W_dt, W_out, WinT, WxT, WdtT, WoutT);

  // Stage 1: RMSNorm -> xn (bf16)
  prep_rms<<<NTOK, 256, 0, stream>>>(x, w_norm, xn);

  // Stage 2: uzg = xn @ W_in + b_in   (M=32768, N=768, K=1024)
  gemm_bf16<0><<<dim3(NTOK / 128, 768 / 128), 256, 0, stream>>>(
      xn, DD, WinT, b_in, uzg, 768, nullptr, DD);

  // Stage 3: ut = tanh(u @ W_x + b_x); dt = sigmoid(z @ W_dt + b_dt)
  gemm_bf16<1><<<dim3(NTOK / 128, SS / 128), 256, 0, stream>>>(
      uzg, 768, WxT, b_x, ut, SS, nullptr, SS);
  gemm_bf16<2><<<dim3(NTOK / 128, SS / 128), 256, 0, stream>>>(
      uzg + SS, 768, WdtT, b_dt, dtb, SS, nullptr, SS);

  // Stage 4: chunked parallel scan + gate (in-place hsg over ut buffer)
  scan_phase_a<<<BB * CCH, 128, 0, stream>>>(ut, dtb, h0s, As);
  scan_phase_b<<<BB, 256, 0, stream>>>(h0s, As, hins);
  scan_phase_c<<<BB * CCH, 128, 0, stream>>>(ut, dtb, uzg + 2 * SS, hins, ut);

  // Stage 5: out = x + hsg @ W_out + b_out  (M=32768, N=1024, K=256)
  gemm_bf16<3><<<dim3(NTOK / 128, DD / 128), 256, 0, stream>>>(
      ut, SS, WoutT, b_out, out, DD, x, SS);
}

// Round 11
// 275.408 us; speedup vs baseline: 1.3621x; 1.0265x over previous
//
#include <hip/hip_runtime.h>
#include <hip/hip_bf16.h>

// Problem constants (B=8, L=4096, D=1024, S=256)
#define BB 8
#define LL 4096
#define DD 1024
#define SS 256
#define NTOK (BB * LL)  // 32768 tokens
#define CCH 64          // chunks per sequence (parallel scan)
#define TCH (LL / CCH)  // 64 timesteps per chunk

typedef short bf16x8 __attribute__((ext_vector_type(8)));
typedef float f32x4 __attribute__((ext_vector_type(4)));

__device__ __forceinline__ float bfu(unsigned short v) {
  union { unsigned int i; float f; } x;
  x.i = ((unsigned int)v) << 16;
  return x.f;
}

// Async global->LDS, 16B per lane. LDS dest is wave-uniform base + lane*16.
__device__ __forceinline__ void gl_lds16(const __hip_bfloat16* g, void* l) {
  __builtin_amdgcn_global_load_lds(
      (const __attribute__((address_space(1))) unsigned int*)g,
      (__attribute__((address_space(3))) unsigned int*)l, 16, 0, 0);
}

// ---------------------------------------------------------------------------
// Kernel 1: RMSNorm + bf16 cast.  One block per token row (D=1024).
// ---------------------------------------------------------------------------
__global__ __launch_bounds__(256) void prep_rms(const float* __restrict__ x,
                                                const float* __restrict__ wn,
                                                __hip_bfloat16* __restrict__ xn) {
  const size_t row = blockIdx.x;
  const int t = threadIdx.x;
  const float4 xv = reinterpret_cast<const float4*>(x + row * DD)[t];
  const float4 wv = reinterpret_cast<const float4*>(wn)[t];
  float ss = xv.x * xv.x + xv.y * xv.y + xv.z * xv.z + xv.w * xv.w;
#pragma unroll
  for (int m = 32; m >= 1; m >>= 1) ss += __shfl_xor(ss, m);
  __shared__ float red[4];
  if ((t & 63) == 0) red[t >> 6] = ss;
  __syncthreads();
  const float tot = red[0] + red[1] + red[2] + red[3];
  const float r = rsqrtf(tot * (1.0f / DD) + 1e-8f);
  union { ushort4 u; __hip_bfloat16 h[4]; } o;
  o.h[0] = __float2bfloat16(xv.x * wv.x * r);
  o.h[1] = __float2bfloat16(xv.y * wv.y * r);
  o.h[2] = __float2bfloat16(xv.z * wv.z * r);
  o.h[3] = __float2bfloat16(xv.w * wv.w * r);
  reinterpret_cast<ushort4*>(xn + row * DD)[t] = o.u;
}

// ---------------------------------------------------------------------------
// Kernel 2: all four weight transposes+casts in one launch (blockIdx.y = seg).
// WT[n*K+k] = bf16(W[k*Nw+n])
// ---------------------------------------------------------------------------
__global__ __launch_bounds__(256) void convT4(
    const float* __restrict__ W0, const float* __restrict__ W1,
    const float* __restrict__ W2, const float* __restrict__ W3,
    __hip_bfloat16* __restrict__ T0, __hip_bfloat16* __restrict__ T1,
    __hip_bfloat16* __restrict__ T2, __hip_bfloat16* __restrict__ T3) {
  const int seg = blockIdx.y;
  const int K = (seg == 0) ? DD : SS;
  const int Nw = (seg == 0) ? 768 : (seg == 3) ? DD : SS;
  const float* W = (seg == 0) ? W0 : (seg == 1) ? W1 : (seg == 2) ? W2 : W3;
  __hip_bfloat16* T = (seg == 0) ? T0 : (seg == 1) ? T1 : (seg == 2) ? T2 : T3;
  const int idx = blockIdx.x * 256 + threadIdx.x;
  if (idx >= K * Nw) return;
  const int k = idx / Nw, n = idx % Nw;
  T[(size_t)n * K + k] = __float2bfloat16(W[idx]);
}

// ---------------------------------------------------------------------------
// Kernel 3: bf16 MFMA GEMM.  C[M,Nt] = epi(A[M,K] @ BT[Nt,K]^T + bias)
// 128x128 tile, 4 waves, BK=64, dbuf LDS, counted vmcnt (T4), both-sides
// XOR swizzle (T2/rule #21), swapped MFMA operands (row=token epilogue).
// EPI 3: NT resid loads + bias, then sched_barrier(0) PIN (compiler cannot
// sink the loads) -> 16 loads in flight per wave; plain f32x4 stores.
// EPI 4: fused g1+g2 (blockIdx.y>>1 selects {WxT,b_x,tanh->ut} vs
// {WdtT,b_dt,sigmoid->dtb}), K=256.
// EPI: 0 = bf16, 1 = tanh, 2 = sigmoid, 3 = +resid->f32, 4 = fused g1/g2
// ---------------------------------------------------------------------------
template <int EPI>
__global__ __launch_bounds__(256, 2) void gemm_bf16(
    const __hip_bfloat16* __restrict__ A, int lda,
    const __hip_bfloat16* __restrict__ BT,  // [Nt][K] (pre-transposed)
    const float* __restrict__ bias,
    void* __restrict__ Cptr, int ldc,
    const float* __restrict__ resid,
    int K,
    const __hip_bfloat16* __restrict__ BT2,
    const float* __restrict__ bias2,
    void* __restrict__ Cptr2) {
  __shared__ __align__(16) char ldsA[2][128 * 128];
  __shared__ __align__(16) char ldsB[2][128 * 128];

  const int t = threadIdx.x;
  const int bm = blockIdx.x;
  const int bn = blockIdx.y;
  const int wave = t >> 6, lane = t & 63;
  const int wr = (wave >> 1) * 64;
  const int wc = (wave & 1) * 64;
  const int lr = lane & 15;
  const int kg = lane >> 4;
  const int rsw = lr & 7;

  // EPI 4: which GEMM (0 = u/tanh, 1 = z/sigmoid); bneff = column tile.
  const int which = (EPI == 4) ? (bn >> 1) : 0;
  const int bneff = (EPI == 4) ? (bn & 1) : bn;
  const __hip_bfloat16* Aeff = (EPI == 4 && which) ? A + SS : A;
  const __hip_bfloat16* BTeff = (EPI == 4 && which) ? BT2 : BT;
  const float* biaseff = (EPI == 4 && which) ? bias2 : bias;
  void* Ceff = (EPI == 4 && which) ? Cptr2 : Cptr;

  const int srow = lane >> 3;
  const int sg = (lane & 7) ^ srow;
  const int g_row = wave * 32 + srow;
  const __hip_bfloat16* Ab = Aeff + (size_t)(bm * 128 + g_row) * lda + sg * 8;
  const __hip_bfloat16* Bb = BTeff + (size_t)(bneff * 128 + g_row) * K + sg * 8;

  f32x4 acc[4][4] = {};

#define STAGE(d, koff)                                                        \
  {                                                                           \
    _Pragma("unroll") for (int p = 0; p < 4; ++p) {                           \
      gl_lds16(Ab + (size_t)(p * 8) * lda + (koff),                           \
               ldsA[d] + (wave * 32 + p * 8) * 128);                          \
      gl_lds16(Bb + (size_t)(p * 8) * K + (koff),                             \
               ldsB[d] + (wave * 32 + p * 8) * 128);                          \
    }                                                                         \
  }

  const int NT = K >> 6;
  STAGE(0, 0);

  for (int ti = 0; ti < NT; ++ti) {
    const int cur = ti & 1;
    if (ti + 1 < NT) {
      STAGE(cur ^ 1, (ti + 1) * 64);
      asm volatile("s_waitcnt vmcnt(8)" ::: "memory");
    } else {
      asm volatile("s_waitcnt vmcnt(0)" ::: "memory");
    }
    __builtin_amdgcn_sched_barrier(0);
    __builtin_amdgcn_s_barrier();
#pragma unroll
    for (int kh = 0; kh < 2; ++kh) {
      bf16x8 af[4], bfr[4];
#pragma unroll
      for (int m = 0; m < 4; ++m) {
        const int row = wr + m * 16 + lr;
        const int slot = (kg + kh * 4) ^ rsw;
        af[m] = *reinterpret_cast<const bf16x8*>(ldsA[cur] + row * 128 + slot * 16);
      }
#pragma unroll
      for (int n = 0; n < 4; ++n) {
        const int row = wc + n * 16 + lr;
        const int slot = (kg + kh * 4) ^ rsw;
        bfr[n] = *reinterpret_cast<const bf16x8*>(ldsB[cur] + row * 128 + slot * 16);
      }
#pragma unroll
      for (int m = 0; m < 4; ++m)
#pragma unroll
        for (int n = 0; n < 4; ++n)
          acc[m][n] = __builtin_amdgcn_mfma_f32_16x16x32_bf16(bfr[n], af[m],
                                                              acc[m][n], 0, 0, 0);
    }
    __builtin_amdgcn_sched_barrier(0);
    __builtin_amdgcn_s_barrier();
  }
#undef STAGE

  // Swapped-operand epilogue:
  // token row = bm*128 + wr + m*16 + (lane&15)
  // C col     = bneff*128 + wc + n*16 + kg*4 + j   (j = 0..3 consecutive)
  const int row0 = bm * 128 + wr + lr;
  const int col0 = bneff * 128 + wc + kg * 4;

  if (EPI == 3) {
    // Issue ALL 16 resid loads (NT) + 4 bias loads, then PIN with
    // sched_barrier(0) so the compiler cannot sink them to their uses.
    f32x4 rv[4][4];
    f32x4 bv[4];
#pragma unroll
    for (int n = 0; n < 4; ++n)
      bv[n] = *reinterpret_cast<const f32x4*>(&bias[col0 + n * 16]);
#pragma unroll
    for (int m = 0; m < 4; ++m) {
      const size_t rowoff = (size_t)(row0 + m * 16) * ldc;
#pragma unroll
      for (int n = 0; n < 4; ++n) {
        rv[m][n] = __builtin_nontemporal_load(
            reinterpret_cast<const f32x4*>(&resid[rowoff + col0 + n * 16]));
      }
    }
    __builtin_amdgcn_sched_barrier(0);  // all 16 loads stay issued up-front
#pragma unroll
    for (int m = 0; m < 4; ++m) {
      const size_t rowoff = (size_t)(row0 + m * 16) * ldc;
#pragma unroll
      for (int n = 0; n < 4; ++n) {
        f32x4 ov = acc[m][n] + bv[n] + rv[m][n];
        *reinterpret_cast<f32x4*>(&((float*)Cptr)[rowoff + col0 + n * 16]) = ov;
      }
    }
  } else {
#pragma unroll
    for (int m = 0; m < 4; ++m) {
      const int row = row0 + m * 16;
#pragma unroll
      for (int n = 0; n < 4; ++n) {
        const int colb = col0 + n * 16;
        const float4 bvv = *reinterpret_cast<const float4*>(&biaseff[colb]);
        float v0 = acc[m][n][0] + bvv.x;
        float v1 = acc[m][n][1] + bvv.y;
        float v2 = acc[m][n][2] + bvv.z;
        float v3 = acc[m][n][3] + bvv.w;
        if (EPI == 1 || (EPI == 4 && which == 0)) {
          v0 = tanhf(v0); v1 = tanhf(v1); v2 = tanhf(v2); v3 = tanhf(v3);
        } else if (EPI == 2 || (EPI == 4 && which == 1)) {
          v0 = 1.f / (1.f + expf(-v0)); v1 = 1.f / (1.f + expf(-v1));
          v2 = 1.f / (1.f + expf(-v2)); v3 = 1.f / (1.f + expf(-v3));
        }
        union { ushort4 u; __hip_bfloat16 h[4]; } o;
        o.h[0] = __float2bfloat16(v0); o.h[1] = __float2bfloat16(v1);
        o.h[2] = __float2bfloat16(v2); o.h[3] = __float2bfloat16(v3);
        *reinterpret_cast<ushort4*>(
            &((__hip_bfloat16*)Ceff)[(size_t)row * ldc + colb]) = o.u;
      }
    }
  }
}

// ---------------------------------------------------------------------------
// Kernel 4a: chunked scan phase A.  Per (b, chunk, s): local scan from h=0
// giving h0, and decay product A = prod(1-d).  2 channels per lane (ushort2).
// ---------------------------------------------------------------------------
__global__ __launch_bounds__(128) void scan_phase_a(
    const __hip_bfloat16* __restrict__ ut,
    const __hip_bfloat16* __restrict__ dtb,
    float* __restrict__ h0s, float* __restrict__ As) {
  const int bc = blockIdx.x;             // b*CCH + c
  const int b = bc / CCH, c = bc % CCH;
  const int ch = threadIdx.x * 2;        // channel pair base
  const size_t base = ((size_t)b * LL + (size_t)c * TCH) * SS + ch;
  float h0 = 0.f, h1 = 0.f, A0 = 1.f, A1 = 1.f;
#pragma unroll 8
  for (int t = 0; t < TCH; ++t) {
    const ushort2 uu = *reinterpret_cast<const ushort2*>(ut + base + (size_t)t * SS);
    const ushort2 dd = *reinterpret_cast<const ushort2*>(dtb + base + (size_t)t * SS);
    const float d0 = bfu(dd.x), d1 = bfu(dd.y);
    h0 = fmaf(d0, bfu(uu.x) - h0, h0);
    h1 = fmaf(d1, bfu(uu.y) - h1, h1);
    A0 *= (1.f - d0);
    A1 *= (1.f - d1);
  }
  const size_t o = (size_t)bc * SS + ch;
  *reinterpret_cast<float2*>(h0s + o) = make_float2(h0, h1);
  *reinterpret_cast<float2*>(As + o) = make_float2(A0, A1);
}

// ---------------------------------------------------------------------------
// Kernel 4b: carry scan over chunk summaries.  Per (b, s): hin_0 = 0,
// hin_{c+1} = h0_c + A_c * hin_c.  Stores hin per (b, c, s).
// ---------------------------------------------------------------------------
__global__ __launch_bounds__(256) void scan_phase_b(
    const float* __restrict__ h0s, const float* __restrict__ As,
    float* __restrict__ hins) {
  const int b = blockIdx.x;
  const int s = threadIdx.x;
  float hin = 0.f;
#pragma unroll 8
  for (int c = 0; c < CCH; ++c) {
    const size_t idx = ((size_t)b * CCH + c) * SS + s;
    hins[idx] = hin;
    hin = fmaf(As[idx], hin, h0s[idx]);
  }
}

// ---------------------------------------------------------------------------
// Kernel 4c: chunked scan phase C.  Re-run each chunk with correct carry-in,
// gate by sigmoid(g), write hsg (in-place over ut: same-thread read-first).
// ---------------------------------------------------------------------------
__global__ __launch_bounds__(128) void scan_phase_c(
    const __hip_bfloat16* __restrict__ ut,
    const __hip_bfloat16* __restrict__ dtb,
    const __hip_bfloat16* __restrict__ gz,   // uzg + 512, row stride 768
    const float* __restrict__ hins,
    __hip_bfloat16* __restrict__ hsg) {
  const int bc = blockIdx.x;
  const int b = bc / CCH, c = bc % CCH;
  const int ch = threadIdx.x * 2;
  const size_t rowbase = (size_t)b * LL + (size_t)c * TCH;
  const float2 hv = *reinterpret_cast<const float2*>(hins + (size_t)bc * SS + ch);
  float h0 = hv.x, h1 = hv.y;
#pragma unroll 8
  for (int t = 0; t < TCH; ++t) {
    const size_t row = rowbase + t;
    const ushort2 uu = *reinterpret_cast<const ushort2*>(ut + row * SS + ch);
    const ushort2 dd = *reinterpret_cast<const ushort2*>(dtb + row * SS + ch);
    const ushort2 gg = *reinterpret_cast<const ushort2*>(gz + row * 768 + ch);
    h0 = fmaf(bfu(dd.x), bfu(uu.x) - h0, h0);
    h1 = fmaf(bfu(dd.y), bfu(uu.y) - h1, h1);
    union { ushort2 u; __hip_bfloat16 h[2]; } o;
    o.h[0] = __float2bfloat16(h0 / (1.f + expf(-bfu(gg.x))));
    o.h[1] = __float2bfloat16(h1 / (1.f + expf(-bfu(gg.y))));
    *reinterpret_cast<ushort2*>(hsg + row * SS + ch) = o.u;
  }
}

// ---------------------------------------------------------------------------
extern "C" void kernel_launch(void* const* d_in, const int* in_sizes, int n_in,
                              void* d_out, int out_size, void* d_ws, size_t ws_size,
                              hipStream_t stream) {
  const float* x      = (const float*)d_in[0];
  const float* w_norm = (const float*)d_in[1];
  const float* W_in   = (const float*)d_in[2];
  const float* b_in   = (const float*)d_in[3];
  const float* W_x    = (const float*)d_in[4];
  const float* b_x    = (const float*)d_in[5];
  const float* W_dt   = (const float*)d_in[6];
  const float* b_dt   = (const float*)d_in[7];
  const float* W_out  = (const float*)d_in[8];
  const float* b_out  = (const float*)d_in[9];
  float* out = (float*)d_out;

  // Workspace layout (bf16 buffers). ut/dt alias the dead xn region.
  char* w = (char*)d_ws;
  __hip_bfloat16* xn  = (__hip_bfloat16*)w;                 // NTOK*1024
  __hip_bfloat16* ut  = (__hip_bfloat16*)w;                 // NTOK*256 (after GEMM1)
  __hip_bfloat16* dtb = (__hip_bfloat16*)(w + (size_t)NTOK * SS * 2);
  w += (size_t)NTOK * DD * 2;                               // 64 MiB
  __hip_bfloat16* uzg = (__hip_bfloat16*)w;  w += (size_t)NTOK * 768 * 2;  // 48 MiB
  __hip_bfloat16* WinT  = (__hip_bfloat16*)w;  w += (size_t)768 * DD * 2;
  __hip_bfloat16* WxT   = (__hip_bfloat16*)w;  w += (size_t)SS * SS * 2;
  __hip_bfloat16* WdtT  = (__hip_bfloat16*)w;  w += (size_t)SS * SS * 2;
  __hip_bfloat16* WoutT = (__hip_bfloat16*)w;  w += (size_t)DD * SS * 2;
  float* h0s  = (float*)w;  w += (size_t)BB * CCH * SS * 4;   // 512 KiB
  float* As   = (float*)w;  w += (size_t)BB * CCH * SS * 4;
  float* hins = (float*)w;  w += (size_t)BB * CCH * SS * 4;
  (void)ws_size; (void)n_in; (void)in_sizes; (void)out_size;

  // Stage 0: all weight conversions in one launch
  convT4<<<dim3((DD * 768 + 255) / 256, 4), 256, 0, stream>>>(
      W_in, W_x, W_dt, W_out, WinT, WxT, WdtT, WoutT);

  // Stage 1: RMSNorm -> xn (bf16)
  prep_rms<<<NTOK, 256, 0, stream>>>(x, w_norm, xn);

  // Stage 2: uzg = xn @ W_in + b_in   (M=32768, N=768, K=1024)
  gemm_bf16<0><<<dim3(NTOK / 128, 768 / 128), 256, 0, stream>>>(
      xn, DD, WinT, b_in, uzg, 768, nullptr, DD, nullptr, nullptr, nullptr);

  // Stage 3 (fused): ut = tanh(u @ W_x + b_x); dt = sigmoid(z @ W_dt + b_dt)
  gemm_bf16<4><<<dim3(NTOK / 128, 4), 256, 0, stream>>>(
      uzg, 768, WxT, b_x, ut, SS, nullptr, SS, WdtT, b_dt, dtb);

  // Stage 4: chunked parallel scan + gate (in-place hsg over ut buffer)
  scan_phase_a<<<BB * CCH, 128, 0, stream>>>(ut, dtb, h0s, As);
  scan_phase_b<<<BB, 256, 0, stream>>>(h0s, As, hins);
  scan_phase_c<<<BB * CCH, 128, 0, stream>>>(ut, dtb, uzg + 2 * SS, hins, ut);

  // Stage 5: out = x + hsg @ W_out + b_out  (M=32768, N=1024, K=256)
  gemm_bf16<3><<<dim3(NTOK / 128, DD / 128), 256, 0, stream>>>(
      ut, SS, WoutT, b_out, out, DD, x, SS, nullptr, nullptr, nullptr);
}